// Round 4
// baseline (383.769 us; speedup 1.0000x reference)
//
#include <hip/hip_runtime.h>

typedef unsigned short u16;
typedef u16 u16x8 __attribute__((ext_vector_type(8)));
typedef u16 u16x4 __attribute__((ext_vector_type(4)));
typedef __bf16 bf16x8 __attribute__((ext_vector_type(8)));
typedef float f32x4 __attribute__((ext_vector_type(4)));

#define DEVI static __device__ __forceinline__

#define BB 32
#define NN 577
#define CC 1024
#define HH 16
#define DD 64
#define MM (BB * NN)   // 18464
#define SCALE_ 0.125f

DEVI u16 f2bf(float f) {
  union { float f; unsigned u; } v; v.f = f;
  unsigned r = v.u + 0x7FFFu + ((v.u >> 16) & 1u);
  return (u16)(r >> 16);
}
DEVI float bf2f(u16 b) {
  union { unsigned u; float f; } v; v.u = ((unsigned)b) << 16; return v.f;
}
DEVI f32x4 mfma16(u16x8 a, u16x8 b, f32x4 c) {
  return __builtin_amdgcn_mfma_f32_16x16x32_bf16(
      __builtin_bit_cast(bf16x8, a), __builtin_bit_cast(bf16x8, b), c, 0, 0, 0);
}
DEVI void gload_lds16(const u16* g, u16* l) {
  __builtin_amdgcn_global_load_lds(
      (const __attribute__((address_space(1))) void*)g,
      (__attribute__((address_space(3))) void*)l, 16, 0, 0);
}

// ---------------- fp32 -> bf16 convert ----------------
__global__ void cvt_kernel(const float* __restrict__ in, u16* __restrict__ out, int n4) {
  int i = blockIdx.x * blockDim.x + threadIdx.x;
  int stride = gridDim.x * blockDim.x;
  for (; i < n4; i += stride) {
    float4 v = ((const float4*)in)[i];
    u16x4 o = { f2bf(v.x), f2bf(v.y), f2bf(v.z), f2bf(v.w) };
    ((u16x4*)out)[i] = o;
  }
}

// ---------------- Pipelined GEMM (T3 2-phase, 256x128 tile, 8 waves) --------
// C[M,N] = A[M,K] * Bw[N,K]^T (+bias). bf16 in, bf16 or f32+bias out.
// K-tile double-buffer (full-tile granularity): stage tile t+1 into buf^1
// while MFMAs consume buf; ONE __syncthreads per K-tile (drains vmcnt).
// T2 XOR swizzle via pre-swizzled global source (linear gload_lds dest).
__global__ __launch_bounds__(512) void gemm_p2(
    const u16* __restrict__ A, const u16* __restrict__ Bw,
    u16* __restrict__ Cb, float* __restrict__ Cf, const float* __restrict__ bias,
    int M, int N, int K, int MT, int NT)
{
  __shared__ u16 Als[2][256 * 64];
  __shared__ u16 Bls[2][128 * 64];

  // bijective XCD swizzle (m204), nt-fastest within an XCD chunk
  int nwg = MT * NT;
  int orig = blockIdx.x;
  int q = nwg >> 3, r = nwg & 7;
  int xcd = orig & 7, idx = orig >> 3;
  int wg = (xcd < r ? xcd * (q + 1) : r * (q + 1) + (xcd - r) * q) + idx;
  int mt = wg / NT, nt = wg % NT;

  const int t = threadIdx.x, lane = t & 63, w = t >> 6;
  const int wr2 = w >> 2, wc2 = w & 3;        // wave grid 2 x 4
  const int fr = lane & 15, fg = lane >> 4;
  const int m0 = mt * 256, n0 = nt * 128;

  f32x4 acc[8][2] = {};

  // staging addresses: load i covers rows i*64 + w*8 + (lane>>3) of the tile,
  // 16B chunk (lane&7); global col pre-swizzled by row&7 (T2, rule #21).
  const int swcol = ((lane & 7) ^ ((lane >> 3) & 7)) * 8;
  const u16* pA[4];
  const u16* pB[2];
#pragma unroll
  for (int i = 0; i < 4; ++i) {
    int row = i * 64 + w * 8 + (lane >> 3);
    int ga = m0 + row; if (ga > M - 1) ga = M - 1;
    pA[i] = A + (size_t)ga * K + swcol;
  }
#pragma unroll
  for (int i = 0; i < 2; ++i) {
    int row = i * 64 + w * 8 + (lane >> 3);
    pB[i] = Bw + (size_t)(n0 + row) * K + swcol;   // N % 128 == 0
  }

  // prologue: stage K-tile 0 into buf 0
#pragma unroll
  for (int i = 0; i < 4; ++i) gload_lds16(pA[i], &Als[0][i * 4096 + w * 512]);
#pragma unroll
  for (int i = 0; i < 2; ++i) gload_lds16(pB[i], &Bls[0][i * 4096 + w * 512]);
  __syncthreads();

  const int c0 = (fg ^ (fr & 7)) * 8;          // swizzled chunk, kk=0
  const int c1 = ((4 + fg) ^ (fr & 7)) * 8;    // swizzled chunk, kk=1
  const int nkt = K >> 6;

  for (int tk = 0; tk < nkt; ++tk) {
    const int cur = tk & 1, nxt = cur ^ 1;
    const u16* Ac = &Als[cur][0];
    const u16* Bc = &Bls[cur][0];
    const int ktn = (tk + 1) << 6;
    const bool more = (tk + 1 < nkt);

    // ---- phase 0: issue A-chunks 0..2 of next tile; compute m=0..3 ----
    if (more) {
      gload_lds16(pA[0] + ktn, &Als[nxt][0 * 4096 + w * 512]);
      gload_lds16(pA[1] + ktn, &Als[nxt][1 * 4096 + w * 512]);
      gload_lds16(pA[2] + ktn, &Als[nxt][2 * 4096 + w * 512]);
    }
    u16x8 b00 = *(const u16x8*)&Bc[(wc2 * 32 +  0 + fr) * 64 + c0];
    u16x8 b01 = *(const u16x8*)&Bc[(wc2 * 32 + 16 + fr) * 64 + c0];
    u16x8 b10 = *(const u16x8*)&Bc[(wc2 * 32 +  0 + fr) * 64 + c1];
    u16x8 b11 = *(const u16x8*)&Bc[(wc2 * 32 + 16 + fr) * 64 + c1];
    {
      u16x8 a0[4], a1[4];
#pragma unroll
      for (int m = 0; m < 4; ++m) {
        int row = wr2 * 128 + m * 16 + fr;
        a0[m] = *(const u16x8*)&Ac[row * 64 + c0];
        a1[m] = *(const u16x8*)&Ac[row * 64 + c1];
      }
      __builtin_amdgcn_s_setprio(1);
#pragma unroll
      for (int m = 0; m < 4; ++m) {
        acc[m][0] = mfma16(a0[m], b00, acc[m][0]);
        acc[m][1] = mfma16(a0[m], b01, acc[m][1]);
        acc[m][0] = mfma16(a1[m], b10, acc[m][0]);
        acc[m][1] = mfma16(a1[m], b11, acc[m][1]);
      }
      __builtin_amdgcn_s_setprio(0);
    }

    // ---- phase 1: issue A-chunk 3 + B-chunks of next tile; compute m=4..7 --
    if (more) {
      gload_lds16(pA[3] + ktn, &Als[nxt][3 * 4096 + w * 512]);
      gload_lds16(pB[0] + ktn, &Bls[nxt][0 * 4096 + w * 512]);
      gload_lds16(pB[1] + ktn, &Bls[nxt][1 * 4096 + w * 512]);
    }
    {
      u16x8 a0[4], a1[4];
#pragma unroll
      for (int m = 0; m < 4; ++m) {
        int row = wr2 * 128 + (m + 4) * 16 + fr;
        a0[m] = *(const u16x8*)&Ac[row * 64 + c0];
        a1[m] = *(const u16x8*)&Ac[row * 64 + c1];
      }
      __builtin_amdgcn_s_setprio(1);
#pragma unroll
      for (int m = 0; m < 4; ++m) {
        acc[m + 4][0] = mfma16(a0[m], b00, acc[m + 4][0]);
        acc[m + 4][1] = mfma16(a0[m], b01, acc[m + 4][1]);
        acc[m + 4][0] = mfma16(a1[m], b10, acc[m + 4][0]);
        acc[m + 4][1] = mfma16(a1[m], b11, acc[m + 4][1]);
      }
      __builtin_amdgcn_s_setprio(0);
    }
    __syncthreads();   // drains vmcnt(0): next buffer complete for all waves
  }

  // epilogue
#pragma unroll
  for (int m = 0; m < 8; ++m) {
#pragma unroll
    for (int j = 0; j < 4; ++j) {
      int row = m0 + wr2 * 128 + m * 16 + fg * 4 + j;
      if (row >= M) continue;
#pragma unroll
      for (int n = 0; n < 2; ++n) {
        int col = n0 + wc2 * 32 + n * 16 + fr;
        float v = acc[m][n][j];
        if (Cf) Cf[(size_t)row * N + col] = v + bias[col];
        else    Cb[(size_t)row * N + col] = f2bf(v);
      }
    }
  }
}

// ---------------- 3x3 avg pool of Xq (24x24 -> 8x8) ----------------
__global__ __launch_bounds__(256) void pool_kernel(const u16* __restrict__ qkv, u16* __restrict__ Qp) {
  int b = blockIdx.x >> 6, pq = blockIdx.x & 63;
  int py = pq >> 3, px = pq & 7;
  int c0 = threadIdx.x * 4;
  float s0 = 0.f, s1 = 0.f, s2 = 0.f, s3 = 0.f;
#pragma unroll
  for (int dy = 0; dy < 3; ++dy)
#pragma unroll
    for (int dx = 0; dx < 3; ++dx) {
      int n = (py * 3 + dy) * 24 + px * 3 + dx;
      u16x4 v = *(const u16x4*)(qkv + (size_t)(b * NN + n) * 3072 + c0);
      s0 += bf2f(v[0]); s1 += bf2f(v[1]); s2 += bf2f(v[2]); s3 += bf2f(v[3]);
    }
  const float r = 1.f / 9.f;
  u16x4 o = { f2bf(s0 * r), f2bf(s1 * r), f2bf(s2 * r), f2bf(s3 * r) };
  *(u16x4*)(Qp + (size_t)(b * 64 + pq) * CC + c0) = o;
}

// ---------------- Stage 1: pooled Q (64) attends to K/V (577) ----------------
__global__ __launch_bounds__(256) void stage1_kernel(
    const u16* __restrict__ qkv, const u16* __restrict__ Qp, u16* __restrict__ QdT)
{
  __shared__ u16 Kls[64][72];
  __shared__ u16 Vt[64][72];     // Vt[dv][key]
  __shared__ u16 Pls[4][16][72];
  int bh = blockIdx.x, b = bh >> 4, h = bh & 15;
  int t = threadIdx.x, lane = t & 63, w = t >> 6;
  int fr = lane & 15, fg = lane >> 4;

  const u16* Qb = Qp + (size_t)(b * 64 + w * 16 + fr) * CC + h * DD;
  u16x8 qf0 = *(const u16x8*)(Qb + fg * 8);
  u16x8 qf1 = *(const u16x8*)(Qb + 32 + fg * 8);

  f32x4 o[4] = {};
  float rowm[4] = {-1e30f, -1e30f, -1e30f, -1e30f};
  float rowl[4] = {};

  for (int kt = 0; kt < 10; ++kt) {
#pragma unroll
    for (int i = 0; i < 2; ++i) {
      int g = t + i * 256;
      int key = g >> 3, cc = (g & 7) * 8;
      int n = kt * 64 + key;
      u16x8 kv = {}, vv = {};
      if (n < NN) {
        const u16* p = qkv + (size_t)(b * NN + n) * 3072 + h * DD + cc;
        kv = *(const u16x8*)(p + CC);
        vv = *(const u16x8*)(p + 2 * CC);
      }
      *(u16x8*)&Kls[key][cc] = kv;
#pragma unroll
      for (int j = 0; j < 8; ++j) Vt[cc + j][key] = vv[j];
    }
    __syncthreads();

    f32x4 s[4] = {};
#pragma unroll
    for (int kk = 0; kk < 2; ++kk) {
      u16x8 qf = kk ? qf1 : qf0;
#pragma unroll
      for (int n = 0; n < 4; ++n) {
        u16x8 kf = *(const u16x8*)&Kls[n * 16 + fr][kk * 32 + fg * 8];
        s[n] = mfma16(qf, kf, s[n]);
      }
    }
    float mx[4] = {-1e30f, -1e30f, -1e30f, -1e30f};
#pragma unroll
    for (int n = 0; n < 4; ++n) {
      int key = kt * 64 + n * 16 + fr;
#pragma unroll
      for (int j = 0; j < 4; ++j) {
        float v = s[n][j] * SCALE_;
        if (key >= NN) v = -1e30f;
        s[n][j] = v;
        mx[j] = fmaxf(mx[j], v);
      }
    }
    for (int d = 1; d < 16; d <<= 1) {
#pragma unroll
      for (int j = 0; j < 4; ++j) mx[j] = fmaxf(mx[j], __shfl_xor(mx[j], d));
    }
    float corr[4];
#pragma unroll
    for (int j = 0; j < 4; ++j) {
      float mn = fmaxf(rowm[j], mx[j]);
      corr[j] = __expf(rowm[j] - mn);
      rowm[j] = mn;
    }
    float rs[4] = {};
#pragma unroll
    for (int n = 0; n < 4; ++n)
#pragma unroll
      for (int j = 0; j < 4; ++j) {
        float p = __expf(s[n][j] - rowm[j]);
        s[n][j] = p;
        rs[j] += p;
      }
    for (int d = 1; d < 16; d <<= 1) {
#pragma unroll
      for (int j = 0; j < 4; ++j) rs[j] += __shfl_xor(rs[j], d);
    }
#pragma unroll
    for (int j = 0; j < 4; ++j) rowl[j] = rowl[j] * corr[j] + rs[j];
#pragma unroll
    for (int n = 0; n < 4; ++n)
#pragma unroll
      for (int j = 0; j < 4; ++j) o[n][j] *= corr[j];

#pragma unroll
    for (int n = 0; n < 4; ++n)
#pragma unroll
      for (int j = 0; j < 4; ++j)
        Pls[w][fg * 4 + j][n * 16 + fr] = f2bf(s[n][j]);
    __syncthreads();

#pragma unroll
    for (int kk = 0; kk < 2; ++kk) {
      u16x8 pf = *(const u16x8*)&Pls[w][fr][kk * 32 + fg * 8];
#pragma unroll
      for (int n = 0; n < 4; ++n) {
        u16x8 vf = *(const u16x8*)&Vt[n * 16 + fr][kk * 32 + fg * 8];
        o[n] = mfma16(pf, vf, o[n]);
      }
    }
    __syncthreads();
  }

#pragma unroll
  for (int n = 0; n < 4; ++n)
#pragma unroll
    for (int j = 0; j < 4; ++j) {
      int dv = n * 16 + fr, q2 = w * 16 + fg * 4 + j;
      QdT[((size_t)bh * 64 + dv) * 64 + q2] = f2bf(o[n][j] / rowl[j]);
    }
}

// ---------------- Stage 2 ----------------
__global__ __launch_bounds__(256) void stage2_kernel(
    const u16* __restrict__ qkv, const u16* __restrict__ Qp,
    const u16* __restrict__ QdT, u16* __restrict__ AO)
{
  __shared__ u16 Qpl[64][72];
  __shared__ u16 Qdl[64][72];
  __shared__ u16 Pls[4][16][72];
  int id = blockIdx.x;
  int ntile = id % 10;
  int bh = id / 10, b = bh >> 4, h = bh & 15;
  int t = threadIdx.x, lane = t & 63, w = t >> 6;
  int fr = lane & 15, fg = lane >> 4;

#pragma unroll
  for (int i = 0; i < 2; ++i) {
    int g = t + i * 256;
    int row = g >> 3, cc = (g & 7) * 8;
    *(u16x8*)&Qpl[row][cc] = *(const u16x8*)(Qp + (size_t)(b * 64 + row) * CC + h * DD + cc);
    *(u16x8*)&Qdl[row][cc] = *(const u16x8*)(QdT + ((size_t)bh * 64 + row) * 64 + cc);
  }
  __syncthreads();

  int n0 = ntile * 64;
  int qrow = n0 + w * 16 + fr;
  int qc = qrow < NN ? qrow : NN - 1;
  const u16* Qb = qkv + (size_t)(b * NN + qc) * 3072 + h * DD;
  u16x8 qf0 = *(const u16x8*)(Qb + fg * 8);
  u16x8 qf1 = *(const u16x8*)(Qb + 32 + fg * 8);

  f32x4 s[4] = {};
#pragma unroll
  for (int kk = 0; kk < 2; ++kk) {
    u16x8 qf = kk ? qf1 : qf0;
#pragma unroll
    for (int n = 0; n < 4; ++n) {
      u16x8 bfrag = *(const u16x8*)&Qpl[n * 16 + fr][kk * 32 + fg * 8];
      s[n] = mfma16(qf, bfrag, s[n]);
    }
  }
  float mx[4] = {-1e30f, -1e30f, -1e30f, -1e30f};
#pragma unroll
  for (int n = 0; n < 4; ++n)
#pragma unroll
    for (int j = 0; j < 4; ++j) {
      float v = s[n][j] * SCALE_;
      s[n][j] = v;
      mx[j] = fmaxf(mx[j], v);
    }
  for (int d = 1; d < 16; d <<= 1) {
#pragma unroll
    for (int j = 0; j < 4; ++j) mx[j] = fmaxf(mx[j], __shfl_xor(mx[j], d));
  }
  float rs[4] = {};
#pragma unroll
  for (int n = 0; n < 4; ++n)
#pragma unroll
    for (int j = 0; j < 4; ++j) {
      float p = __expf(s[n][j] - mx[j]);
      s[n][j] = p;
      rs[j] += p;
    }
  for (int d = 1; d < 16; d <<= 1) {
#pragma unroll
    for (int j = 0; j < 4; ++j) rs[j] += __shfl_xor(rs[j], d);
  }

#pragma unroll
  for (int n = 0; n < 4; ++n)
#pragma unroll
    for (int j = 0; j < 4; ++j)
      Pls[w][fg * 4 + j][n * 16 + fr] = f2bf(s[n][j]);
  __syncthreads();

  f32x4 of[4] = {};
#pragma unroll
  for (int kk = 0; kk < 2; ++kk) {
    u16x8 pf = *(const u16x8*)&Pls[w][fr][kk * 32 + fg * 8];
#pragma unroll
    for (int n = 0; n < 4; ++n) {
      u16x8 qd = *(const u16x8*)&Qdl[n * 16 + fr][kk * 32 + fg * 8];
      of[n] = mfma16(pf, qd, of[n]);
    }
  }

#pragma unroll
  for (int n = 0; n < 4; ++n)
#pragma unroll
    for (int j = 0; j < 4; ++j) {
      int orow = n0 + w * 16 + fg * 4 + j;
      if (orow < NN)
        AO[(size_t)(b * NN + orow) * CC + h * DD + n * 16 + fr] = f2bf(of[n][j] / rs[j]);
    }
}

// ---------------- launch ----------------
extern "C" void kernel_launch(void* const* d_in, const int* in_sizes, int n_in,
                              void* d_out, int out_size, void* d_ws, size_t ws_size,
                              hipStream_t stream) {
  const float* X     = (const float*)d_in[0];
  const float* Wqkv  = (const float*)d_in[1];
  const float* Wproj = (const float*)d_in[2];
  const float* bproj = (const float*)d_in[3];

  char* ws = (char*)d_ws;
  u16* Xb  = (u16*)(ws + 0);            // 18464*1024*2 = 37,814,272
  u16* Wqb = (u16*)(ws + 37814272);     // 3072*1024*2  =  6,291,456
  u16* Wpb = (u16*)(ws + 44105728);     // 1024*1024*2  =  2,097,152
  u16* qkv = (u16*)(ws + 46202880);     // 18464*3072*2 = 113,442,816
  u16* Qpb = (u16*)(ws + 159645696);    // 32*64*1024*2 =  4,194,304
  u16* QdT = (u16*)(ws + 163840000);    // 512*64*64*2  =  4,194,304
  u16* AO  = (u16*)(ws + 168034304);    // 18464*1024*2 = 37,814,272

  cvt_kernel<<<2048, 256, 0, stream>>>(X, Xb, (BB * NN * CC) / 4);
  cvt_kernel<<<1024, 256, 0, stream>>>(Wqkv, Wqb, (3 * CC * CC) / 4);
  cvt_kernel<<<512, 256, 0, stream>>>(Wproj, Wpb, (CC * CC) / 4);

  gemm_p2<<<73 * 24, 512, 0, stream>>>(Xb, Wqb, qkv, nullptr, nullptr,
                                       MM, 3 * CC, CC, 73, 24);

  pool_kernel<<<BB * 64, 256, 0, stream>>>(qkv, Qpb);
  stage1_kernel<<<BB * HH, 256, 0, stream>>>(qkv, Qpb, QdT);
  stage2_kernel<<<BB * HH * 10, 256, 0, stream>>>(qkv, Qpb, QdT, AO);

  gemm_p2<<<73 * 8, 512, 0, stream>>>(AO, Wpb, nullptr, (float*)d_out, bproj,
                                      MM, CC, CC, 73, 8);
}

// Round 5
// 377.873 us; speedup vs baseline: 1.0156x; 1.0156x over previous
//
#include <hip/hip_runtime.h>

typedef unsigned short u16;
typedef u16 u16x8 __attribute__((ext_vector_type(8)));
typedef u16 u16x4 __attribute__((ext_vector_type(4)));
typedef __bf16 bf16x8 __attribute__((ext_vector_type(8)));
typedef float f32x4 __attribute__((ext_vector_type(4)));

#define DEVI static __device__ __forceinline__

#define BB 32
#define NN 577
#define CC 1024
#define HH 16
#define DD 64
#define MM (BB * NN)   // 18464
#define SCALE_ 0.125f

DEVI u16 f2bf(float f) {
  union { float f; unsigned u; } v; v.f = f;
  unsigned r = v.u + 0x7FFFu + ((v.u >> 16) & 1u);
  return (u16)(r >> 16);
}
DEVI float bf2f(u16 b) {
  union { unsigned u; float f; } v; v.u = ((unsigned)b) << 16; return v.f;
}
DEVI f32x4 mfma16(u16x8 a, u16x8 b, f32x4 c) {
  return __builtin_amdgcn_mfma_f32_16x16x32_bf16(
      __builtin_bit_cast(bf16x8, a), __builtin_bit_cast(bf16x8, b), c, 0, 0, 0);
}
DEVI void gload_lds16(const u16* g, u16* l) {
  __builtin_amdgcn_global_load_lds(
      (const __attribute__((address_space(1))) void*)g,
      (__attribute__((address_space(3))) void*)l, 16, 0, 0);
}

// ---------------- fp32 -> bf16 convert ----------------
__global__ void cvt_kernel(const float* __restrict__ in, u16* __restrict__ out, int n4) {
  int i = blockIdx.x * blockDim.x + threadIdx.x;
  int stride = gridDim.x * blockDim.x;
  for (; i < n4; i += stride) {
    float4 v = ((const float4*)in)[i];
    u16x4 o = { f2bf(v.x), f2bf(v.y), f2bf(v.z), f2bf(v.w) };
    ((u16x4*)out)[i] = o;
  }
}

// ---- Pipelined GEMM: 256x256 tile, BK=32, 8 waves, 3-buffer depth-2 prefetch.
// C[M,N] = A[M,K] * Bw[N,K]^T (+bias).
// Never drains vmcnt in the main loop (counted vmcnt(4); vmcnt(0) only on the
// last K-step). One raw s_barrier per K-step. T2 chunk-XOR swizzle staged via
// pre-swizzled global source (linear gload_lds dest).
__global__ __launch_bounds__(512, 2) void gemm_p3(
    const u16* __restrict__ A, const u16* __restrict__ Bw,
    u16* __restrict__ Cb, float* __restrict__ Cf, const float* __restrict__ bias,
    int M, int N, int K, int MT, int NT)
{
  __shared__ u16 Als[3][256 * 32];
  __shared__ u16 Bls[3][256 * 32];

  // bijective XCD swizzle (m204)
  int nwg = MT * NT;
  int orig = blockIdx.x;
  int q = nwg >> 3, r = nwg & 7;
  int xcd = orig & 7, idx = orig >> 3;
  int wg = (xcd < r ? xcd * (q + 1) : r * (q + 1) + (xcd - r) * q) + idx;
  int mt = wg / NT, nt = wg % NT;

  const int t = threadIdx.x, lane = t & 63, w = t >> 6;
  const int wr2 = w >> 2, wc2 = w & 3;        // 2 (M) x 4 (N) wave grid
  const int fr = lane & 15, fg = lane >> 4;
  const int m0 = mt * 256, n0 = nt * 256;

  f32x4 acc[8][4] = {};

  // staging: instr i of wave w covers tile rows w*32 + i*16 + (lane>>2),
  // physical 8-elem chunk (lane&3). Global logical chunk is pre-swizzled:
  // chunk_log = (lane&3) ^ ((row>>1)&3) = (lane&3) ^ ((lane>>3)&3).
  const int srccol = ((lane & 3) ^ ((lane >> 3) & 3)) * 8;
  const u16* pA[2];
  const u16* pB[2];
#pragma unroll
  for (int i = 0; i < 2; ++i) {
    int row = w * 32 + i * 16 + (lane >> 2);
    int ga = m0 + row; if (ga > M - 1) ga = M - 1;
    pA[i] = A + (size_t)ga * K + srccol;
    pB[i] = Bw + (size_t)(n0 + row) * K + srccol;   // N % 256 == 0
  }

  auto stage = [&](int tk, int bi) {
    const int kc = tk << 5;
#pragma unroll
    for (int i = 0; i < 2; ++i) {
      gload_lds16(pA[i] + kc, &Als[bi][w * 1024 + i * 512]);
      gload_lds16(pB[i] + kc, &Bls[bi][w * 1024 + i * 512]);
    }
  };

  // prologue: tiles 0 and 1 in flight (8 loads/wave outstanding)
  stage(0, 0);
  stage(1, 1);

  const int nkt = K >> 5;          // 32
  const int ch = fg ^ ((fr >> 1) & 3);   // swizzled chunk for frag reads
  int cur = 0;

  for (int tk = 0; tk < nkt; ++tk) {
    // wait: tile tk's 4 loads retired; tiles tk+1 (and soon tk+2) in flight
    if (tk + 1 < nkt) asm volatile("s_waitcnt vmcnt(4)" ::: "memory");
    else              asm volatile("s_waitcnt vmcnt(0)" ::: "memory");
    __builtin_amdgcn_sched_barrier(0);
    __builtin_amdgcn_s_barrier();
    __builtin_amdgcn_sched_barrier(0);

    // issue prefetch for tile tk+2 into buffer (cur+2)%3 (read last at tk-1,
    // all waves' reads completed before the barrier above)
    int pre = cur + 2; if (pre >= 3) pre -= 3;
    if (tk + 2 < nkt) stage(tk + 2, pre);

    // compute K-step tk from buffer cur
    const u16* Ac = &Als[cur][0];
    const u16* Bc = &Bls[cur][0];
    u16x8 bf_[4], af[8];
#pragma unroll
    for (int n = 0; n < 4; ++n)
      bf_[n] = *(const u16x8*)&Bc[(wc2 * 64 + n * 16 + fr) * 32 + ch * 8];
#pragma unroll
    for (int m = 0; m < 8; ++m)
      af[m] = *(const u16x8*)&Ac[(wr2 * 128 + m * 16 + fr) * 32 + ch * 8];
    __builtin_amdgcn_s_setprio(1);
#pragma unroll
    for (int m = 0; m < 8; ++m)
#pragma unroll
      for (int n = 0; n < 4; ++n)
        acc[m][n] = mfma16(af[m], bf_[n], acc[m][n]);
    __builtin_amdgcn_s_setprio(0);

    if (++cur == 3) cur = 0;
  }

  // epilogue
#pragma unroll
  for (int m = 0; m < 8; ++m) {
#pragma unroll
    for (int j = 0; j < 4; ++j) {
      int row = m0 + wr2 * 128 + m * 16 + fg * 4 + j;
      if (row >= M) continue;
#pragma unroll
      for (int n = 0; n < 4; ++n) {
        int col = n0 + wc2 * 64 + n * 16 + fr;
        float v = acc[m][n][j];
        if (Cf) Cf[(size_t)row * N + col] = v + bias[col];
        else    Cb[(size_t)row * N + col] = f2bf(v);
      }
    }
  }
}

// ---------------- 3x3 avg pool of Xq (24x24 -> 8x8) ----------------
__global__ __launch_bounds__(256) void pool_kernel(const u16* __restrict__ qkv, u16* __restrict__ Qp) {
  int b = blockIdx.x >> 6, pq = blockIdx.x & 63;
  int py = pq >> 3, px = pq & 7;
  int c0 = threadIdx.x * 4;
  float s0 = 0.f, s1 = 0.f, s2 = 0.f, s3 = 0.f;
#pragma unroll
  for (int dy = 0; dy < 3; ++dy)
#pragma unroll
    for (int dx = 0; dx < 3; ++dx) {
      int n = (py * 3 + dy) * 24 + px * 3 + dx;
      u16x4 v = *(const u16x4*)(qkv + (size_t)(b * NN + n) * 3072 + c0);
      s0 += bf2f(v[0]); s1 += bf2f(v[1]); s2 += bf2f(v[2]); s3 += bf2f(v[3]);
    }
  const float r = 1.f / 9.f;
  u16x4 o = { f2bf(s0 * r), f2bf(s1 * r), f2bf(s2 * r), f2bf(s3 * r) };
  *(u16x4*)(Qp + (size_t)(b * 64 + pq) * CC + c0) = o;
}

// ---------------- Stage 1: pooled Q (64) attends to K/V (577) ----------------
__global__ __launch_bounds__(256) void stage1_kernel(
    const u16* __restrict__ qkv, const u16* __restrict__ Qp, u16* __restrict__ QdT)
{
  __shared__ u16 Kls[64][72];
  __shared__ u16 Vt[64][72];     // Vt[dv][key]
  __shared__ u16 Pls[4][16][72];
  int bh = blockIdx.x, b = bh >> 4, h = bh & 15;
  int t = threadIdx.x, lane = t & 63, w = t >> 6;
  int fr = lane & 15, fg = lane >> 4;

  const u16* Qb = Qp + (size_t)(b * 64 + w * 16 + fr) * CC + h * DD;
  u16x8 qf0 = *(const u16x8*)(Qb + fg * 8);
  u16x8 qf1 = *(const u16x8*)(Qb + 32 + fg * 8);

  f32x4 o[4] = {};
  float rowm[4] = {-1e30f, -1e30f, -1e30f, -1e30f};
  float rowl[4] = {};

  for (int kt = 0; kt < 10; ++kt) {
#pragma unroll
    for (int i = 0; i < 2; ++i) {
      int g = t + i * 256;
      int key = g >> 3, cc = (g & 7) * 8;
      int n = kt * 64 + key;
      u16x8 kv = {}, vv = {};
      if (n < NN) {
        const u16* p = qkv + (size_t)(b * NN + n) * 3072 + h * DD + cc;
        kv = *(const u16x8*)(p + CC);
        vv = *(const u16x8*)(p + 2 * CC);
      }
      *(u16x8*)&Kls[key][cc] = kv;
#pragma unroll
      for (int j = 0; j < 8; ++j) Vt[cc + j][key] = vv[j];
    }
    __syncthreads();

    f32x4 s[4] = {};
#pragma unroll
    for (int kk = 0; kk < 2; ++kk) {
      u16x8 qf = kk ? qf1 : qf0;
#pragma unroll
      for (int n = 0; n < 4; ++n) {
        u16x8 kf = *(const u16x8*)&Kls[n * 16 + fr][kk * 32 + fg * 8];
        s[n] = mfma16(qf, kf, s[n]);
      }
    }
    float mx[4] = {-1e30f, -1e30f, -1e30f, -1e30f};
#pragma unroll
    for (int n = 0; n < 4; ++n) {
      int key = kt * 64 + n * 16 + fr;
#pragma unroll
      for (int j = 0; j < 4; ++j) {
        float v = s[n][j] * SCALE_;
        if (key >= NN) v = -1e30f;
        s[n][j] = v;
        mx[j] = fmaxf(mx[j], v);
      }
    }
    for (int d = 1; d < 16; d <<= 1) {
#pragma unroll
      for (int j = 0; j < 4; ++j) mx[j] = fmaxf(mx[j], __shfl_xor(mx[j], d));
    }
    float corr[4];
#pragma unroll
    for (int j = 0; j < 4; ++j) {
      float mn = fmaxf(rowm[j], mx[j]);
      corr[j] = __expf(rowm[j] - mn);
      rowm[j] = mn;
    }
    float rs[4] = {};
#pragma unroll
    for (int n = 0; n < 4; ++n)
#pragma unroll
      for (int j = 0; j < 4; ++j) {
        float p = __expf(s[n][j] - rowm[j]);
        s[n][j] = p;
        rs[j] += p;
      }
    for (int d = 1; d < 16; d <<= 1) {
#pragma unroll
      for (int j = 0; j < 4; ++j) rs[j] += __shfl_xor(rs[j], d);
    }
#pragma unroll
    for (int j = 0; j < 4; ++j) rowl[j] = rowl[j] * corr[j] + rs[j];
#pragma unroll
    for (int n = 0; n < 4; ++n)
#pragma unroll
      for (int j = 0; j < 4; ++j) o[n][j] *= corr[j];

#pragma unroll
    for (int n = 0; n < 4; ++n)
#pragma unroll
      for (int j = 0; j < 4; ++j)
        Pls[w][fg * 4 + j][n * 16 + fr] = f2bf(s[n][j]);
    __syncthreads();

#pragma unroll
    for (int kk = 0; kk < 2; ++kk) {
      u16x8 pf = *(const u16x8*)&Pls[w][fr][kk * 32 + fg * 8];
#pragma unroll
      for (int n = 0; n < 4; ++n) {
        u16x8 vf = *(const u16x8*)&Vt[n * 16 + fr][kk * 32 + fg * 8];
        o[n] = mfma16(pf, vf, o[n]);
      }
    }
    __syncthreads();
  }

#pragma unroll
  for (int n = 0; n < 4; ++n)
#pragma unroll
    for (int j = 0; j < 4; ++j) {
      int dv = n * 16 + fr, q2 = w * 16 + fg * 4 + j;
      QdT[((size_t)bh * 64 + dv) * 64 + q2] = f2bf(o[n][j] / rowl[j]);
    }
}

// ---------------- Stage 2 ----------------
__global__ __launch_bounds__(256) void stage2_kernel(
    const u16* __restrict__ qkv, const u16* __restrict__ Qp,
    const u16* __restrict__ QdT, u16* __restrict__ AO)
{
  __shared__ u16 Qpl[64][72];
  __shared__ u16 Qdl[64][72];
  __shared__ u16 Pls[4][16][72];
  int id = blockIdx.x;
  int ntile = id % 10;
  int bh = id / 10, b = bh >> 4, h = bh & 15;
  int t = threadIdx.x, lane = t & 63, w = t >> 6;
  int fr = lane & 15, fg = lane >> 4;

#pragma unroll
  for (int i = 0; i < 2; ++i) {
    int g = t + i * 256;
    int row = g >> 3, cc = (g & 7) * 8;
    *(u16x8*)&Qpl[row][cc] = *(const u16x8*)(Qp + (size_t)(b * 64 + row) * CC + h * DD + cc);
    *(u16x8*)&Qdl[row][cc] = *(const u16x8*)(QdT + ((size_t)bh * 64 + row) * 64 + cc);
  }
  __syncthreads();

  int n0 = ntile * 64;
  int qrow = n0 + w * 16 + fr;
  int qc = qrow < NN ? qrow : NN - 1;
  const u16* Qb = qkv + (size_t)(b * NN + qc) * 3072 + h * DD;
  u16x8 qf0 = *(const u16x8*)(Qb + fg * 8);
  u16x8 qf1 = *(const u16x8*)(Qb + 32 + fg * 8);

  f32x4 s[4] = {};
#pragma unroll
  for (int kk = 0; kk < 2; ++kk) {
    u16x8 qf = kk ? qf1 : qf0;
#pragma unroll
    for (int n = 0; n < 4; ++n) {
      u16x8 bfrag = *(const u16x8*)&Qpl[n * 16 + fr][kk * 32 + fg * 8];
      s[n] = mfma16(qf, bfrag, s[n]);
    }
  }
  float mx[4] = {-1e30f, -1e30f, -1e30f, -1e30f};
#pragma unroll
  for (int n = 0; n < 4; ++n)
#pragma unroll
    for (int j = 0; j < 4; ++j) {
      float v = s[n][j] * SCALE_;
      s[n][j] = v;
      mx[j] = fmaxf(mx[j], v);
    }
  for (int d = 1; d < 16; d <<= 1) {
#pragma unroll
    for (int j = 0; j < 4; ++j) mx[j] = fmaxf(mx[j], __shfl_xor(mx[j], d));
  }
  float rs[4] = {};
#pragma unroll
  for (int n = 0; n < 4; ++n)
#pragma unroll
    for (int j = 0; j < 4; ++j) {
      float p = __expf(s[n][j] - mx[j]);
      s[n][j] = p;
      rs[j] += p;
    }
  for (int d = 1; d < 16; d <<= 1) {
#pragma unroll
    for (int j = 0; j < 4; ++j) rs[j] += __shfl_xor(rs[j], d);
  }

#pragma unroll
  for (int n = 0; n < 4; ++n)
#pragma unroll
    for (int j = 0; j < 4; ++j)
      Pls[w][fg * 4 + j][n * 16 + fr] = f2bf(s[n][j]);
  __syncthreads();

  f32x4 of[4] = {};
#pragma unroll
  for (int kk = 0; kk < 2; ++kk) {
    u16x8 pf = *(const u16x8*)&Pls[w][fr][kk * 32 + fg * 8];
#pragma unroll
    for (int n = 0; n < 4; ++n) {
      u16x8 qd = *(const u16x8*)&Qdl[n * 16 + fr][kk * 32 + fg * 8];
      of[n] = mfma16(pf, qd, of[n]);
    }
  }

#pragma unroll
  for (int n = 0; n < 4; ++n)
#pragma unroll
    for (int j = 0; j < 4; ++j) {
      int orow = n0 + w * 16 + fg * 4 + j;
      if (orow < NN)
        AO[(size_t)(b * NN + orow) * CC + h * DD + n * 16 + fr] = f2bf(of[n][j] / rs[j]);
    }
}

// ---------------- launch ----------------
extern "C" void kernel_launch(void* const* d_in, const int* in_sizes, int n_in,
                              void* d_out, int out_size, void* d_ws, size_t ws_size,
                              hipStream_t stream) {
  const float* X     = (const float*)d_in[0];
  const float* Wqkv  = (const float*)d_in[1];
  const float* Wproj = (const float*)d_in[2];
  const float* bproj = (const float*)d_in[3];

  char* ws = (char*)d_ws;
  u16* Xb  = (u16*)(ws + 0);            // 18464*1024*2 = 37,814,272
  u16* Wqb = (u16*)(ws + 37814272);     // 3072*1024*2  =  6,291,456
  u16* Wpb = (u16*)(ws + 44105728);     // 1024*1024*2  =  2,097,152
  u16* qkv = (u16*)(ws + 46202880);     // 18464*3072*2 = 113,442,816
  u16* Qpb = (u16*)(ws + 159645696);    // 32*64*1024*2 =  4,194,304
  u16* QdT = (u16*)(ws + 163840000);    // 512*64*64*2  =  4,194,304
  u16* AO  = (u16*)(ws + 168034304);    // 18464*1024*2 = 37,814,272

  cvt_kernel<<<2048, 256, 0, stream>>>(X, Xb, (BB * NN * CC) / 4);
  cvt_kernel<<<1024, 256, 0, stream>>>(Wqkv, Wqb, (3 * CC * CC) / 4);
  cvt_kernel<<<512, 256, 0, stream>>>(Wproj, Wpb, (CC * CC) / 4);

  // QKV: M=18464 (73 row tiles of 256), N=3072 (12 col tiles)
  gemm_p3<<<73 * 12, 512, 0, stream>>>(Xb, Wqb, qkv, nullptr, nullptr,
                                       MM, 3 * CC, CC, 73, 12);

  pool_kernel<<<BB * 64, 256, 0, stream>>>(qkv, Qpb);
  stage1_kernel<<<BB * HH, 256, 0, stream>>>(qkv, Qpb, QdT);
  stage2_kernel<<<BB * HH * 10, 256, 0, stream>>>(qkv, Qpb, QdT, AO);

  // proj: N=1024 (4 col tiles)
  gemm_p3<<<73 * 4, 512, 0, stream>>>(AO, Wpb, nullptr, (float*)d_out, bproj,
                                      MM, CC, CC, 73, 4);
}

// Round 6
// 300.407 us; speedup vs baseline: 1.2775x; 1.2579x over previous
//
#include <hip/hip_runtime.h>

typedef unsigned short u16;
typedef u16 u16x8 __attribute__((ext_vector_type(8)));
typedef u16 u16x4 __attribute__((ext_vector_type(4)));
typedef __bf16 bf16x8 __attribute__((ext_vector_type(8)));
typedef float f32x4 __attribute__((ext_vector_type(4)));

#define DEVI static __device__ __forceinline__

#define BB 32
#define NN 577
#define CC 1024
#define HH 16
#define DD 64
#define MM (BB * NN)   // 18464
#define SCALE_ 0.125f

DEVI u16 f2bf(float f) {
  union { float f; unsigned u; } v; v.f = f;
  unsigned r = v.u + 0x7FFFu + ((v.u >> 16) & 1u);
  return (u16)(r >> 16);
}
DEVI float bf2f(u16 b) {
  union { unsigned u; float f; } v; v.u = ((unsigned)b) << 16; return v.f;
}
DEVI f32x4 mfma16(u16x8 a, u16x8 b, f32x4 c) {
  return __builtin_amdgcn_mfma_f32_16x16x32_bf16(
      __builtin_bit_cast(bf16x8, a), __builtin_bit_cast(bf16x8, b), c, 0, 0, 0);
}
DEVI void gload_lds16(const u16* g, u16* l) {
  __builtin_amdgcn_global_load_lds(
      (const __attribute__((address_space(1))) void*)g,
      (__attribute__((address_space(3))) void*)l, 16, 0, 0);
}
DEVI void bar() {
  __builtin_amdgcn_sched_barrier(0);
  __builtin_amdgcn_s_barrier();
  __builtin_amdgcn_sched_barrier(0);
}

// ---------------- fp32 -> bf16 convert ----------------
__global__ void cvt_kernel(const float* __restrict__ in, u16* __restrict__ out, int n4) {
  int i = blockIdx.x * blockDim.x + threadIdx.x;
  int stride = gridDim.x * blockDim.x;
  for (; i < n4; i += stride) {
    float4 v = ((const float4*)in)[i];
    u16x4 o = { f2bf(v.x), f2bf(v.y), f2bf(v.z), f2bf(v.w) };
    ((u16x4*)out)[i] = o;
  }
}

// ======== 4-phase interleaved GEMM (T2+T3+T4+T5), 256x256, BK=64, 8 waves ====
// C[M,N] = A[M,K]*Bw[N,K]^T, bf16 out. LDS: per operand a 4-slot ring of
// 256x32 (16 KB) K-half units. Per K-tile: 4 phases, each {ds_read frags |
// stage 1 unit (2 gload_lds) | barrier | 16 MFMA | [vmcnt(8)] barrier}.
// Stage schedule (phase of tile t): ph0:A(t+1,k1) ph1:B(t+1,k1)
//   ph2:A(t+2,k0) ph3:B(t+2,k0). Unit slot = (2*tile+kh)&3.
// Lifetimes: unit (t,k0) read ph0-ph1 of t; (t,k1) read ph2-ph3. Every stage
// lands >=1 barrier-bounded phase after the slot's last reader.
// vmcnt(8) before barrier2 of ph1 (guards ph2 reads) and ph3 (guards next
// ph0 reads): exactly 4 units (8 loads) issued since the consumed unit.
__global__ __launch_bounds__(512, 2) void gemm_p4(
    const u16* __restrict__ A, const u16* __restrict__ Bw,
    u16* __restrict__ Cb, int M, int N, int K, int MT, int NT)
{
  __shared__ u16 Als[4][8192];
  __shared__ u16 Bls[4][8192];

  // bijective XCD swizzle (m204)
  int nwg = MT * NT;
  int orig = blockIdx.x;
  int q = nwg >> 3, r = nwg & 7;
  int xcd = orig & 7, idx = orig >> 3;
  int wg = (xcd < r ? xcd * (q + 1) : r * (q + 1) + (xcd - r) * q) + idx;
  int mt = wg / NT, nt = wg % NT;

  const int t = threadIdx.x, lane = t & 63, w = t >> 6;
  const int wr2 = w >> 2, wc2 = w & 3;      // 2(M) x 4(N) wave grid
  const int fr = lane & 15, fg = lane >> 4;
  const int m0 = mt * 256, n0 = nt * 256;

  f32x4 acc[8][4] = {};

  // ---- staging setup (rule #21: linear LDS dest, pre-swizzled global col) --
  // unit = 256 rows x 32 cols bf16 (16 KB) = 2 gload_lds/thread (j=0,1).
  // thread writes LDS row j*128 + w*16 + (lane>>2), phys chunk (lane&3);
  // logical chunk = (lane&3) ^ ((row>>1)&3) = (lane&3) ^ ((lane>>3)&3).
  const int srccol = ((lane & 3) ^ ((lane >> 3) & 3)) * 8;
  int rA0 = m0 + w * 16 + (lane >> 2);
  int rA1 = rA0 + 128;
  if (rA0 > M - 1) rA0 = M - 1;
  if (rA1 > M - 1) rA1 = M - 1;
  const u16* pA0 = A + (size_t)rA0 * K + srccol;
  const u16* pA1 = A + (size_t)rA1 * K + srccol;
  const u16* pB0 = Bw + (size_t)(n0 + w * 16 + (lane >> 2)) * K + srccol;
  const u16* pB1 = pB0 + (size_t)128 * K;
  const int ldsoff = w * 512;                 // elems: (w*64 lanes)*8

  auto stageA = [&](int tile, int kh, int slot) {
    const int col = tile * 64 + kh * 32;
    gload_lds16(pA0 + col, &Als[slot][ldsoff]);
    gload_lds16(pA1 + col, &Als[slot][4096 + ldsoff]);
  };
  auto stageB = [&](int tile, int kh, int slot) {
    const int col = tile * 64 + kh * 32;
    gload_lds16(pB0 + col, &Bls[slot][ldsoff]);
    gload_lds16(pB1 + col, &Bls[slot][4096 + ldsoff]);
  };

  // ---- fragment read offsets (swizzled, conflict-free per round-5 PMC) ----
  const int swch8 = (fg ^ ((fr >> 1) & 3)) * 8;
  const int aoff = (wr2 * 128 + fr) * 32 + swch8;   // + m*512
  const int boff = (wc2 * 64 + fr) * 32 + swch8;    // + n*512

  const int nkt = K >> 6;   // 16

  // ---- prologue: 6 units in steady-state issue order ----
  stageA(0, 0, 0); stageB(0, 0, 0);
  stageA(0, 1, 1); stageB(0, 1, 1);
  stageA(1, 0, 2); stageB(1, 0, 2);
  asm volatile("s_waitcnt vmcnt(8)" ::: "memory");  // A(0,k0),B(0,k0) landed
  bar();

  for (int tk = 0; tk < nkt; ++tk) {
    const int s0 = (2 * tk) & 3, s1 = (2 * tk + 1) & 3, s3 = (2 * tk + 3) & 3;
    const int t1 = (tk + 1 < nkt) ? tk + 1 : 0;              // wrap -> dummy
    const int t2 = (tk + 2 < nkt) ? tk + 2 : tk + 2 - nkt;   // into dead slot
    u16x8 a[4], b[4];

    // ---- phase 0: frags(m0-3,kk0)+B(kk0); stage A(t+1,k1); MFMA q0 ----
#pragma unroll
    for (int m = 0; m < 4; ++m) a[m] = *(const u16x8*)&Als[s0][aoff + m * 512];
#pragma unroll
    for (int n = 0; n < 4; ++n) b[n] = *(const u16x8*)&Bls[s0][boff + n * 512];
    stageA(t1, 1, s3);
    bar();
    __builtin_amdgcn_s_setprio(1);
#pragma unroll
    for (int m = 0; m < 4; ++m)
#pragma unroll
      for (int n = 0; n < 4; ++n)
        acc[m][n] = mfma16(a[m], b[n], acc[m][n]);
    __builtin_amdgcn_s_setprio(0);
    bar();

    // ---- phase 1: frags(m4-7,kk0); stage B(t+1,k1); MFMA q1; vmcnt ----
#pragma unroll
    for (int m = 0; m < 4; ++m) a[m] = *(const u16x8*)&Als[s0][aoff + (m + 4) * 512];
    stageB(t1, 1, s3);
    bar();
    __builtin_amdgcn_s_setprio(1);
#pragma unroll
    for (int m = 0; m < 4; ++m)
#pragma unroll
      for (int n = 0; n < 4; ++n)
        acc[m + 4][n] = mfma16(a[m], b[n], acc[m + 4][n]);
    __builtin_amdgcn_s_setprio(0);
    asm volatile("s_waitcnt vmcnt(8)" ::: "memory");  // (t,k1) units landed
    bar();

    // ---- phase 2: frags(m0-3,kk1)+B(kk1); stage A(t+2,k0); MFMA q2 ----
#pragma unroll
    for (int m = 0; m < 4; ++m) a[m] = *(const u16x8*)&Als[s1][aoff + m * 512];
#pragma unroll
    for (int n = 0; n < 4; ++n) b[n] = *(const u16x8*)&Bls[s1][boff + n * 512];
    stageA(t2, 0, s0);
    bar();
    __builtin_amdgcn_s_setprio(1);
#pragma unroll
    for (int m = 0; m < 4; ++m)
#pragma unroll
      for (int n = 0; n < 4; ++n)
        acc[m][n] = mfma16(a[m], b[n], acc[m][n]);
    __builtin_amdgcn_s_setprio(0);
    bar();

    // ---- phase 3: frags(m4-7,kk1); stage B(t+2,k0); MFMA q3; vmcnt ----
#pragma unroll
    for (int m = 0; m < 4; ++m) a[m] = *(const u16x8*)&Als[s1][aoff + (m + 4) * 512];
    stageB(t2, 0, s0);
    bar();
    __builtin_amdgcn_s_setprio(1);
#pragma unroll
    for (int m = 0; m < 4; ++m)
#pragma unroll
      for (int n = 0; n < 4; ++n)
        acc[m + 4][n] = mfma16(a[m], b[n], acc[m + 4][n]);
    __builtin_amdgcn_s_setprio(0);
    asm volatile("s_waitcnt vmcnt(8)" ::: "memory");  // (t+1,k0) units landed
    bar();
  }

  // ---- epilogue ----
#pragma unroll
  for (int m = 0; m < 8; ++m) {
#pragma unroll
    for (int j = 0; j < 4; ++j) {
      int row = m0 + wr2 * 128 + m * 16 + fg * 4 + j;
      if (row >= M) continue;
#pragma unroll
      for (int n = 0; n < 4; ++n) {
        int col = n0 + wc2 * 64 + n * 16 + fr;
        Cb[(size_t)row * N + col] = f2bf(acc[m][n][j]);
      }
    }
  }
}

// ---------------- GEMM (round-3 m97 structure + T2 swizzle) -----------------
__global__ __launch_bounds__(256) void gemm_bt2(
    const u16* __restrict__ A, const u16* __restrict__ Bw,
    u16* __restrict__ Cb, float* __restrict__ Cf, const float* __restrict__ bias,
    int M, int N, int K, int MT, int NT)
{
  __shared__ u16 Als[128 * 64];
  __shared__ u16 Bls[128 * 64];

  int nwg = MT * NT;
  int orig = blockIdx.x;
  int q = nwg >> 3, r = nwg & 7;
  int xcd = orig & 7, idx = orig >> 3;
  int wg = (xcd < r ? xcd * (q + 1) : r * (q + 1) + (xcd - r) * q) + idx;
  int mt = wg / NT, nt = wg % NT;

  const int t = threadIdx.x, lane = t & 63, w = t >> 6;
  const int wr = (w >> 1) * 64, wc = (w & 1) * 64;
  const int fr = lane & 15, fg = lane >> 4;
  const int m0 = mt * 128, n0 = nt * 128;
  f32x4 acc[4][4] = {};

  const int swcol = ((lane & 7) ^ ((lane >> 3) & 7)) * 8;
  const u16* pA[4];
  const u16* pB[4];
#pragma unroll
  for (int i = 0; i < 4; ++i) {
    int row = w * 32 + i * 8 + (lane >> 3);
    int ga = m0 + row; if (ga > M - 1) ga = M - 1;
    pA[i] = A + (size_t)ga * K + swcol;
    pB[i] = Bw + (size_t)(n0 + row) * K + swcol;
  }

  for (int kt = 0; kt < K; kt += 64) {
#pragma unroll
    for (int i = 0; i < 4; ++i) {
      int c = w * 4 + i;
      gload_lds16(pA[i] + kt, &Als[c * 512]);
      gload_lds16(pB[i] + kt, &Bls[c * 512]);
    }
    __syncthreads();
#pragma unroll
    for (int kk = 0; kk < 2; ++kk) {
      u16x8 af[4], bfr[4];
#pragma unroll
      for (int m = 0; m < 4; ++m) {
        int row = wr + m * 16 + fr;
        int ch = (kk * 4 + fg) ^ (fr & 7);
        af[m] = *(const u16x8*)&Als[row * 64 + ch * 8];
      }
#pragma unroll
      for (int n = 0; n < 4; ++n) {
        int row = wc + n * 16 + fr;
        int ch = (kk * 4 + fg) ^ (fr & 7);
        bfr[n] = *(const u16x8*)&Bls[row * 64 + ch * 8];
      }
#pragma unroll
      for (int m = 0; m < 4; ++m)
#pragma unroll
        for (int n = 0; n < 4; ++n)
          acc[m][n] = mfma16(af[m], bfr[n], acc[m][n]);
    }
    __syncthreads();
  }

#pragma unroll
  for (int m = 0; m < 4; ++m) {
#pragma unroll
    for (int j = 0; j < 4; ++j) {
      int row = m0 + wr + m * 16 + fg * 4 + j;
      if (row >= M) continue;
#pragma unroll
      for (int n = 0; n < 4; ++n) {
        int col = n0 + wc + n * 16 + fr;
        float v = acc[m][n][j];
        if (Cf) Cf[(size_t)row * N + col] = v + bias[col];
        else    Cb[(size_t)row * N + col] = f2bf(v);
      }
    }
  }
}

// ---------------- 3x3 avg pool of Xq (24x24 -> 8x8) ----------------
__global__ __launch_bounds__(256) void pool_kernel(const u16* __restrict__ qkv, u16* __restrict__ Qp) {
  int b = blockIdx.x >> 6, pq = blockIdx.x & 63;
  int py = pq >> 3, px = pq & 7;
  int c0 = threadIdx.x * 4;
  float s0 = 0.f, s1 = 0.f, s2 = 0.f, s3 = 0.f;
#pragma unroll
  for (int dy = 0; dy < 3; ++dy)
#pragma unroll
    for (int dx = 0; dx < 3; ++dx) {
      int n = (py * 3 + dy) * 24 + px * 3 + dx;
      u16x4 v = *(const u16x4*)(qkv + (size_t)(b * NN + n) * 3072 + c0);
      s0 += bf2f(v[0]); s1 += bf2f(v[1]); s2 += bf2f(v[2]); s3 += bf2f(v[3]);
    }
  const float r = 1.f / 9.f;
  u16x4 o = { f2bf(s0 * r), f2bf(s1 * r), f2bf(s2 * r), f2bf(s3 * r) };
  *(u16x4*)(Qp + (size_t)(b * 64 + pq) * CC + c0) = o;
}

// ---------------- Stage 1: pooled Q (64) attends to K/V (577) ----------------
__global__ __launch_bounds__(256) void stage1_kernel(
    const u16* __restrict__ qkv, const u16* __restrict__ Qp, u16* __restrict__ QdT)
{
  __shared__ u16 Kls[64][72];
  __shared__ u16 Vt[64][72];     // Vt[dv][key]
  __shared__ u16 Pls[4][16][72];
  int bh = blockIdx.x, b = bh >> 4, h = bh & 15;
  int t = threadIdx.x, lane = t & 63, w = t >> 6;
  int fr = lane & 15, fg = lane >> 4;

  const u16* Qb = Qp + (size_t)(b * 64 + w * 16 + fr) * CC + h * DD;
  u16x8 qf0 = *(const u16x8*)(Qb + fg * 8);
  u16x8 qf1 = *(const u16x8*)(Qb + 32 + fg * 8);

  f32x4 o[4] = {};
  float rowm[4] = {-1e30f, -1e30f, -1e30f, -1e30f};
  float rowl[4] = {};

  for (int kt = 0; kt < 10; ++kt) {
#pragma unroll
    for (int i = 0; i < 2; ++i) {
      int g = t + i * 256;
      int key = g >> 3, cc = (g & 7) * 8;
      int n = kt * 64 + key;
      u16x8 kv = {}, vv = {};
      if (n < NN) {
        const u16* p = qkv + (size_t)(b * NN + n) * 3072 + h * DD + cc;
        kv = *(const u16x8*)(p + CC);
        vv = *(const u16x8*)(p + 2 * CC);
      }
      *(u16x8*)&Kls[key][cc] = kv;
#pragma unroll
      for (int j = 0; j < 8; ++j) Vt[cc + j][key] = vv[j];
    }
    __syncthreads();

    f32x4 s[4] = {};
#pragma unroll
    for (int kk = 0; kk < 2; ++kk) {
      u16x8 qf = kk ? qf1 : qf0;
#pragma unroll
      for (int n = 0; n < 4; ++n) {
        u16x8 kf = *(const u16x8*)&Kls[n * 16 + fr][kk * 32 + fg * 8];
        s[n] = mfma16(qf, kf, s[n]);
      }
    }
    float mx[4] = {-1e30f, -1e30f, -1e30f, -1e30f};
#pragma unroll
    for (int n = 0; n < 4; ++n) {
      int key = kt * 64 + n * 16 + fr;
#pragma unroll
      for (int j = 0; j < 4; ++j) {
        float v = s[n][j] * SCALE_;
        if (key >= NN) v = -1e30f;
        s[n][j] = v;
        mx[j] = fmaxf(mx[j], v);
      }
    }
    for (int d = 1; d < 16; d <<= 1) {
#pragma unroll
      for (int j = 0; j < 4; ++j) mx[j] = fmaxf(mx[j], __shfl_xor(mx[j], d));
    }
    float corr[4];
#pragma unroll
    for (int j = 0; j < 4; ++j) {
      float mn = fmaxf(rowm[j], mx[j]);
      corr[j] = __expf(rowm[j] - mn);
      rowm[j] = mn;
    }
    float rs[4] = {};
#pragma unroll
    for (int n = 0; n < 4; ++n)
#pragma unroll
      for (int j = 0; j < 4; ++j) {
        float p = __expf(s[n][j] - rowm[j]);
        s[n][j] = p;
        rs[j] += p;
      }
    for (int d = 1; d < 16; d <<= 1) {
#pragma unroll
      for (int j = 0; j < 4; ++j) rs[j] += __shfl_xor(rs[j], d);
    }
#pragma unroll
    for (int j = 0; j < 4; ++j) rowl[j] = rowl[j] * corr[j] + rs[j];
#pragma unroll
    for (int n = 0; n < 4; ++n)
#pragma unroll
      for (int j = 0; j < 4; ++j) o[n][j] *= corr[j];

#pragma unroll
    for (int n = 0; n < 4; ++n)
#pragma unroll
      for (int j = 0; j < 4; ++j)
        Pls[w][fg * 4 + j][n * 16 + fr] = f2bf(s[n][j]);
    __syncthreads();

#pragma unroll
    for (int kk = 0; kk < 2; ++kk) {
      u16x8 pf = *(const u16x8*)&Pls[w][fr][kk * 32 + fg * 8];
#pragma unroll
      for (int n = 0; n < 4; ++n) {
        u16x8 vf = *(const u16x8*)&Vt[n * 16 + fr][kk * 32 + fg * 8];
        o[n] = mfma16(pf, vf, o[n]);
      }
    }
    __syncthreads();
  }

#pragma unroll
  for (int n = 0; n < 4; ++n)
#pragma unroll
    for (int j = 0; j < 4; ++j) {
      int dv = n * 16 + fr, q2 = w * 16 + fg * 4 + j;
      QdT[((size_t)bh * 64 + dv) * 64 + q2] = f2bf(o[n][j] / rowl[j]);
    }
}

// ---------------- Stage 2 ----------------
__global__ __launch_bounds__(256) void stage2_kernel(
    const u16* __restrict__ qkv, const u16* __restrict__ Qp,
    const u16* __restrict__ QdT, u16* __restrict__ AO)
{
  __shared__ u16 Qpl[64][72];
  __shared__ u16 Qdl[64][72];
  __shared__ u16 Pls[4][16][72];
  int id = blockIdx.x;
  int ntile = id % 10;
  int bh = id / 10, b = bh >> 4, h = bh & 15;
  int t = threadIdx.x, lane = t & 63, w = t >> 6;
  int fr = lane & 15, fg = lane >> 4;

#pragma unroll
  for (int i = 0; i < 2; ++i) {
    int g = t + i * 256;
    int row = g >> 3, cc = (g & 7) * 8;
    *(u16x8*)&Qpl[row][cc] = *(const u16x8*)(Qp + (size_t)(b * 64 + row) * CC + h * DD + cc);
    *(u16x8*)&Qdl[row][cc] = *(const u16x8*)(QdT + ((size_t)bh * 64 + row) * 64 + cc);
  }
  __syncthreads();

  int n0 = ntile * 64;
  int qrow = n0 + w * 16 + fr;
  int qc = qrow < NN ? qrow : NN - 1;
  const u16* Qb = qkv + (size_t)(b * NN + qc) * 3072 + h * DD;
  u16x8 qf0 = *(const u16x8*)(Qb + fg * 8);
  u16x8 qf1 = *(const u16x8*)(Qb + 32 + fg * 8);

  f32x4 s[4] = {};
#pragma unroll
  for (int kk = 0; kk < 2; ++kk) {
    u16x8 qf = kk ? qf1 : qf0;
#pragma unroll
    for (int n = 0; n < 4; ++n) {
      u16x8 bfrag = *(const u16x8*)&Qpl[n * 16 + fr][kk * 32 + fg * 8];
      s[n] = mfma16(qf, bfrag, s[n]);
    }
  }
  float mx[4] = {-1e30f, -1e30f, -1e30f, -1e30f};
#pragma unroll
  for (int n = 0; n < 4; ++n)
#pragma unroll
    for (int j = 0; j < 4; ++j) {
      float v = s[n][j] * SCALE_;
      s[n][j] = v;
      mx[j] = fmaxf(mx[j], v);
    }
  for (int d = 1; d < 16; d <<= 1) {
#pragma unroll
    for (int j = 0; j < 4; ++j) mx[j] = fmaxf(mx[j], __shfl_xor(mx[j], d));
  }
  float rs[4] = {};
#pragma unroll
  for (int n = 0; n < 4; ++n)
#pragma unroll
    for (int j = 0; j < 4; ++j) {
      float p = __expf(s[n][j] - mx[j]);
      s[n][j] = p;
      rs[j] += p;
    }
  for (int d = 1; d < 16; d <<= 1) {
#pragma unroll
    for (int j = 0; j < 4; ++j) rs[j] += __shfl_xor(rs[j], d);
  }

#pragma unroll
  for (int n = 0; n < 4; ++n)
#pragma unroll
    for (int j = 0; j < 4; ++j)
      Pls[w][fg * 4 + j][n * 16 + fr] = f2bf(s[n][j]);
  __syncthreads();

  f32x4 of[4] = {};
#pragma unroll
  for (int kk = 0; kk < 2; ++kk) {
    u16x8 pf = *(const u16x8*)&Pls[w][fr][kk * 32 + fg * 8];
#pragma unroll
    for (int n = 0; n < 4; ++n) {
      u16x8 qd = *(const u16x8*)&Qdl[n * 16 + fr][kk * 32 + fg * 8];
      of[n] = mfma16(pf, qd, of[n]);
    }
  }

#pragma unroll
  for (int n = 0; n < 4; ++n)
#pragma unroll
    for (int j = 0; j < 4; ++j) {
      int orow = n0 + w * 16 + fg * 4 + j;
      if (orow < NN)
        AO[(size_t)(b * NN + orow) * CC + h * DD + n * 16 + fr] = f2bf(of[n][j] / rs[j]);
    }
}

// ---------------- launch ----------------
extern "C" void kernel_launch(void* const* d_in, const int* in_sizes, int n_in,
                              void* d_out, int out_size, void* d_ws, size_t ws_size,
                              hipStream_t stream) {
  const float* X     = (const float*)d_in[0];
  const float* Wqkv  = (const float*)d_in[1];
  const float* Wproj = (const float*)d_in[2];
  const float* bproj = (const float*)d_in[3];

  char* ws = (char*)d_ws;
  u16* Xb  = (u16*)(ws + 0);            // 18464*1024*2 = 37,814,272
  u16* Wqb = (u16*)(ws + 37814272);     // 3072*1024*2  =  6,291,456
  u16* Wpb = (u16*)(ws + 44105728);     // 1024*1024*2  =  2,097,152
  u16* qkv = (u16*)(ws + 46202880);     // 18464*3072*2 = 113,442,816
  u16* Qpb = (u16*)(ws + 159645696);    // 32*64*1024*2 =  4,194,304
  u16* QdT = (u16*)(ws + 163840000);    // 512*64*64*2  =  4,194,304
  u16* AO  = (u16*)(ws + 168034304);    // 18464*1024*2 = 37,814,272

  cvt_kernel<<<2048, 256, 0, stream>>>(X, Xb, (BB * NN * CC) / 4);
  cvt_kernel<<<1024, 256, 0, stream>>>(Wqkv, Wqb, (3 * CC * CC) / 4);
  cvt_kernel<<<512, 256, 0, stream>>>(Wproj, Wpb, (CC * CC) / 4);

  // QKV: 8-phase-style interleaved 256x256 kernel (73 x 12 tiles)
  gemm_p4<<<73 * 12, 512, 0, stream>>>(Xb, Wqb, qkv, MM, 3 * CC, CC, 73, 12);

  pool_kernel<<<BB * 64, 256, 0, stream>>>(qkv, Qpb);
  stage1_kernel<<<BB * HH, 256, 0, stream>>>(qkv, Qpb, QdT);
  stage2_kernel<<<BB * HH * 10, 256, 0, stream>>>(qkv, Qpb, QdT, AO);

  // proj: proven round-3 structure (145 x 8 tiles)
  gemm_bt2<<<145 * 8, 256, 0, stream>>>(AO, Wpb, nullptr, (float*)d_out, bproj,
                                        MM, CC, CC, 145, 8);
}

// Round 7
// 297.710 us; speedup vs baseline: 1.2891x; 1.0091x over previous
//
#include <hip/hip_runtime.h>

typedef unsigned short u16;
typedef u16 u16x8 __attribute__((ext_vector_type(8)));
typedef u16 u16x4 __attribute__((ext_vector_type(4)));
typedef __bf16 bf16x8 __attribute__((ext_vector_type(8)));
typedef float f32x4 __attribute__((ext_vector_type(4)));

#define DEVI static __device__ __forceinline__

#define BB 32
#define NN 577
#define CC 1024
#define HH 16
#define DD 64
#define MM (BB * NN)   // 18464
#define SCALE_ 0.125f

DEVI u16 f2bf(float f) {
  union { float f; unsigned u; } v; v.f = f;
  unsigned r = v.u + 0x7FFFu + ((v.u >> 16) & 1u);
  return (u16)(r >> 16);
}
DEVI float bf2f(u16 b) {
  union { unsigned u; float f; } v; v.u = ((unsigned)b) << 16; return v.f;
}
DEVI f32x4 mfma16(u16x8 a, u16x8 b, f32x4 c) {
  return __builtin_amdgcn_mfma_f32_16x16x32_bf16(
      __builtin_bit_cast(bf16x8, a), __builtin_bit_cast(bf16x8, b), c, 0, 0, 0);
}
DEVI void gload_lds16(const u16* g, u16* l) {
  __builtin_amdgcn_global_load_lds(
      (const __attribute__((address_space(1))) void*)g,
      (__attribute__((address_space(3))) void*)l, 16, 0, 0);
}
// light barrier: memory-op ordering WITHOUT sched_barrier pinning (m141 trap)
DEVI void fencec() { asm volatile("" ::: "memory"); }
DEVI void lbar() { fencec(); __builtin_amdgcn_s_barrier(); fencec(); }

// ---------------- fp32 -> bf16 convert ----------------
__global__ void cvt_kernel(const float* __restrict__ in, u16* __restrict__ out, int n4) {
  int i = blockIdx.x * blockDim.x + threadIdx.x;
  int stride = gridDim.x * blockDim.x;
  for (; i < n4; i += stride) {
    float4 v = ((const float4*)in)[i];
    u16x4 o = { f2bf(v.x), f2bf(v.y), f2bf(v.z), f2bf(v.w) };
    ((u16x4*)out)[i] = o;
  }
}

// ======== 4-phase interleaved GEMM (T2+T3+T4+T5), 256x256, BK=64, 8 waves ====
// Same schedule/hazard ledger as round 6; barriers are now LIGHT (raw
// s_barrier + compiler memory fence), letting the compiler interleave
// ds_read / gload_lds / MFMA within each phase (m201-style).
__global__ __launch_bounds__(512, 2) void gemm_p4(
    const u16* __restrict__ A, const u16* __restrict__ Bw,
    u16* __restrict__ Cb, int M, int N, int K, int MT, int NT)
{
  __shared__ u16 Als[4][8192];
  __shared__ u16 Bls[4][8192];

  // bijective XCD swizzle (m204)
  int nwg = MT * NT;
  int orig = blockIdx.x;
  int q = nwg >> 3, r = nwg & 7;
  int xcd = orig & 7, idx = orig >> 3;
  int wg = (xcd < r ? xcd * (q + 1) : r * (q + 1) + (xcd - r) * q) + idx;
  int mt = wg / NT, nt = wg % NT;

  const int t = threadIdx.x, lane = t & 63, w = t >> 6;
  const int wr2 = w >> 2, wc2 = w & 3;      // 2(M) x 4(N) wave grid
  const int fr = lane & 15, fg = lane >> 4;
  const int m0 = mt * 256, n0 = nt * 256;

  f32x4 acc[8][4] = {};

  // staging (rule #21: linear LDS dest, pre-swizzled global col)
  const int srccol = ((lane & 3) ^ ((lane >> 3) & 3)) * 8;
  int rA0 = m0 + w * 16 + (lane >> 2);
  int rA1 = rA0 + 128;
  if (rA0 > M - 1) rA0 = M - 1;
  if (rA1 > M - 1) rA1 = M - 1;
  const u16* pA0 = A + (size_t)rA0 * K + srccol;
  const u16* pA1 = A + (size_t)rA1 * K + srccol;
  const u16* pB0 = Bw + (size_t)(n0 + w * 16 + (lane >> 2)) * K + srccol;
  const u16* pB1 = pB0 + (size_t)128 * K;
  const int ldsoff = w * 512;

  auto stageA = [&](int tile, int kh, int slot) {
    const int col = tile * 64 + kh * 32;
    gload_lds16(pA0 + col, &Als[slot][ldsoff]);
    gload_lds16(pA1 + col, &Als[slot][4096 + ldsoff]);
  };
  auto stageB = [&](int tile, int kh, int slot) {
    const int col = tile * 64 + kh * 32;
    gload_lds16(pB0 + col, &Bls[slot][ldsoff]);
    gload_lds16(pB1 + col, &Bls[slot][4096 + ldsoff]);
  };

  const int swch8 = (fg ^ ((fr >> 1) & 3)) * 8;
  const int aoff = (wr2 * 128 + fr) * 32 + swch8;   // + m*512
  const int boff = (wc2 * 64 + fr) * 32 + swch8;    // + n*512

  const int nkt = K >> 6;   // 16

  // prologue: 6 units in flight
  stageA(0, 0, 0); stageB(0, 0, 0);
  stageA(0, 1, 1); stageB(0, 1, 1);
  stageA(1, 0, 2); stageB(1, 0, 2);
  asm volatile("s_waitcnt vmcnt(8)" ::: "memory");  // (0,k0) units landed
  lbar();

  for (int tk = 0; tk < nkt; ++tk) {
    const int s0 = (2 * tk) & 3, s1 = (2 * tk + 1) & 3, s3 = (2 * tk + 3) & 3;
    const int t1 = (tk + 1 < nkt) ? tk + 1 : 0;              // wrap -> dummy
    const int t2 = (tk + 2 < nkt) ? tk + 2 : tk + 2 - nkt;   // into dead slot
    u16x8 a[4], b[4];

    // ---- phase 0: frags(m0-3,kk0)+B(kk0); stage A(t+1,k1); MFMA q0 ----
#pragma unroll
    for (int m = 0; m < 4; ++m) a[m] = *(const u16x8*)&Als[s0][aoff + m * 512];
#pragma unroll
    for (int n = 0; n < 4; ++n) b[n] = *(const u16x8*)&Bls[s0][boff + n * 512];
    stageA(t1, 1, s3);
    lbar();
    __builtin_amdgcn_s_setprio(1);
#pragma unroll
    for (int m = 0; m < 4; ++m)
#pragma unroll
      for (int n = 0; n < 4; ++n)
        acc[m][n] = mfma16(a[m], b[n], acc[m][n]);
    __builtin_amdgcn_s_setprio(0);
    lbar();

    // ---- phase 1: frags(m4-7,kk0); stage B(t+1,k1); MFMA q1; vmcnt ----
#pragma unroll
    for (int m = 0; m < 4; ++m) a[m] = *(const u16x8*)&Als[s0][aoff + (m + 4) * 512];
    stageB(t1, 1, s3);
    lbar();
    __builtin_amdgcn_s_setprio(1);
#pragma unroll
    for (int m = 0; m < 4; ++m)
#pragma unroll
      for (int n = 0; n < 4; ++n)
        acc[m + 4][n] = mfma16(a[m], b[n], acc[m + 4][n]);
    __builtin_amdgcn_s_setprio(0);
    asm volatile("s_waitcnt vmcnt(8)" ::: "memory");  // (t,k1) units landed
    lbar();

    // ---- phase 2: frags(m0-3,kk1)+B(kk1); stage A(t+2,k0); MFMA q2 ----
#pragma unroll
    for (int m = 0; m < 4; ++m) a[m] = *(const u16x8*)&Als[s1][aoff + m * 512];
#pragma unroll
    for (int n = 0; n < 4; ++n) b[n] = *(const u16x8*)&Bls[s1][boff + n * 512];
    stageA(t2, 0, s0);
    lbar();
    __builtin_amdgcn_s_setprio(1);
#pragma unroll
    for (int m = 0; m < 4; ++m)
#pragma unroll
      for (int n = 0; n < 4; ++n)
        acc[m][n] = mfma16(a[m], b[n], acc[m][n]);
    __builtin_amdgcn_s_setprio(0);
    lbar();

    // ---- phase 3: frags(m4-7,kk1); stage B(t+2,k0); MFMA q3; vmcnt ----
#pragma unroll
    for (int m = 0; m < 4; ++m) a[m] = *(const u16x8*)&Als[s1][aoff + (m + 4) * 512];
    stageB(t2, 0, s0);
    lbar();
    __builtin_amdgcn_s_setprio(1);
#pragma unroll
    for (int m = 0; m < 4; ++m)
#pragma unroll
      for (int n = 0; n < 4; ++n)
        acc[m + 4][n] = mfma16(a[m], b[n], acc[m + 4][n]);
    __builtin_amdgcn_s_setprio(0);
    asm volatile("s_waitcnt vmcnt(8)" ::: "memory");  // (t+1,k0) units landed
    lbar();
  }

  // epilogue
#pragma unroll
  for (int m = 0; m < 8; ++m) {
#pragma unroll
    for (int j = 0; j < 4; ++j) {
      int row = m0 + wr2 * 128 + m * 16 + fg * 4 + j;
      if (row >= M) continue;
#pragma unroll
      for (int n = 0; n < 4; ++n) {
        int col = n0 + wc2 * 64 + n * 16 + fr;
        Cb[(size_t)row * N + col] = f2bf(acc[m][n][j]);
      }
    }
  }
}

// ---------------- GEMM (round-3 m97 structure + T2 swizzle) -----------------
__global__ __launch_bounds__(256) void gemm_bt2(
    const u16* __restrict__ A, const u16* __restrict__ Bw,
    u16* __restrict__ Cb, float* __restrict__ Cf, const float* __restrict__ bias,
    int M, int N, int K, int MT, int NT)
{
  __shared__ u16 Als[128 * 64];
  __shared__ u16 Bls[128 * 64];

  int nwg = MT * NT;
  int orig = blockIdx.x;
  int q = nwg >> 3, r = nwg & 7;
  int xcd = orig & 7, idx = orig >> 3;
  int wg = (xcd < r ? xcd * (q + 1) : r * (q + 1) + (xcd - r) * q) + idx;
  int mt = wg / NT, nt = wg % NT;

  const int t = threadIdx.x, lane = t & 63, w = t >> 6;
  const int wr = (w >> 1) * 64, wc = (w & 1) * 64;
  const int fr = lane & 15, fg = lane >> 4;
  const int m0 = mt * 128, n0 = nt * 128;
  f32x4 acc[4][4] = {};

  const int swcol = ((lane & 7) ^ ((lane >> 3) & 7)) * 8;
  const u16* pA[4];
  const u16* pB[4];
#pragma unroll
  for (int i = 0; i < 4; ++i) {
    int row = w * 32 + i * 8 + (lane >> 3);
    int ga = m0 + row; if (ga > M - 1) ga = M - 1;
    pA[i] = A + (size_t)ga * K + swcol;
    pB[i] = Bw + (size_t)(n0 + row) * K + swcol;
  }

  for (int kt = 0; kt < K; kt += 64) {
#pragma unroll
    for (int i = 0; i < 4; ++i) {
      int c = w * 4 + i;
      gload_lds16(pA[i] + kt, &Als[c * 512]);
      gload_lds16(pB[i] + kt, &Bls[c * 512]);
    }
    __syncthreads();
#pragma unroll
    for (int kk = 0; kk < 2; ++kk) {
      u16x8 af[4], bfr[4];
#pragma unroll
      for (int m = 0; m < 4; ++m) {
        int row = wr + m * 16 + fr;
        int ch = (kk * 4 + fg) ^ (fr & 7);
        af[m] = *(const u16x8*)&Als[row * 64 + ch * 8];
      }
#pragma unroll
      for (int n = 0; n < 4; ++n) {
        int row = wc + n * 16 + fr;
        int ch = (kk * 4 + fg) ^ (fr & 7);
        bfr[n] = *(const u16x8*)&Bls[row * 64 + ch * 8];
      }
#pragma unroll
      for (int m = 0; m < 4; ++m)
#pragma unroll
        for (int n = 0; n < 4; ++n)
          acc[m][n] = mfma16(af[m], bfr[n], acc[m][n]);
    }
    __syncthreads();
  }

#pragma unroll
  for (int m = 0; m < 4; ++m) {
#pragma unroll
    for (int j = 0; j < 4; ++j) {
      int row = m0 + wr + m * 16 + fg * 4 + j;
      if (row >= M) continue;
#pragma unroll
      for (int n = 0; n < 4; ++n) {
        int col = n0 + wc + n * 16 + fr;
        float v = acc[m][n][j];
        if (Cf) Cf[(size_t)row * N + col] = v + bias[col];
        else    Cb[(size_t)row * N + col] = f2bf(v);
      }
    }
  }
}

// ---------------- 3x3 avg pool of Xq (24x24 -> 8x8) ----------------
__global__ __launch_bounds__(256) void pool_kernel(const u16* __restrict__ qkv, u16* __restrict__ Qp) {
  int b = blockIdx.x >> 6, pq = blockIdx.x & 63;
  int py = pq >> 3, px = pq & 7;
  int c0 = threadIdx.x * 4;
  float s0 = 0.f, s1 = 0.f, s2 = 0.f, s3 = 0.f;
#pragma unroll
  for (int dy = 0; dy < 3; ++dy)
#pragma unroll
    for (int dx = 0; dx < 3; ++dx) {
      int n = (py * 3 + dy) * 24 + px * 3 + dx;
      u16x4 v = *(const u16x4*)(qkv + (size_t)(b * NN + n) * 3072 + c0);
      s0 += bf2f(v[0]); s1 += bf2f(v[1]); s2 += bf2f(v[2]); s3 += bf2f(v[3]);
    }
  const float r = 1.f / 9.f;
  u16x4 o = { f2bf(s0 * r), f2bf(s1 * r), f2bf(s2 * r), f2bf(s3 * r) };
  *(u16x4*)(Qp + (size_t)(b * 64 + pq) * CC + c0) = o;
}

// ---------------- Stage 1: pooled Q (64) attends to K/V (577) ----------------
__global__ __launch_bounds__(256) void stage1_kernel(
    const u16* __restrict__ qkv, const u16* __restrict__ Qp, u16* __restrict__ QdT)
{
  __shared__ u16 Kls[64][72];
  __shared__ u16 Vt[64][72];     // Vt[dv][key]
  __shared__ u16 Pls[4][16][72];
  int bh = blockIdx.x, b = bh >> 4, h = bh & 15;
  int t = threadIdx.x, lane = t & 63, w = t >> 6;
  int fr = lane & 15, fg = lane >> 4;

  const u16* Qb = Qp + (size_t)(b * 64 + w * 16 + fr) * CC + h * DD;
  u16x8 qf0 = *(const u16x8*)(Qb + fg * 8);
  u16x8 qf1 = *(const u16x8*)(Qb + 32 + fg * 8);

  f32x4 o[4] = {};
  float rowm[4] = {-1e30f, -1e30f, -1e30f, -1e30f};
  float rowl[4] = {};

  for (int kt = 0; kt < 10; ++kt) {
#pragma unroll
    for (int i = 0; i < 2; ++i) {
      int g = t + i * 256;
      int key = g >> 3, cc = (g & 7) * 8;
      int n = kt * 64 + key;
      u16x8 kv = {}, vv = {};
      if (n < NN) {
        const u16* p = qkv + (size_t)(b * NN + n) * 3072 + h * DD + cc;
        kv = *(const u16x8*)(p + CC);
        vv = *(const u16x8*)(p + 2 * CC);
      }
      *(u16x8*)&Kls[key][cc] = kv;
#pragma unroll
      for (int j = 0; j < 8; ++j) Vt[cc + j][key] = vv[j];
    }
    __syncthreads();

    f32x4 s[4] = {};
#pragma unroll
    for (int kk = 0; kk < 2; ++kk) {
      u16x8 qf = kk ? qf1 : qf0;
#pragma unroll
      for (int n = 0; n < 4; ++n) {
        u16x8 kf = *(const u16x8*)&Kls[n * 16 + fr][kk * 32 + fg * 8];
        s[n] = mfma16(qf, kf, s[n]);
      }
    }
    float mx[4] = {-1e30f, -1e30f, -1e30f, -1e30f};
#pragma unroll
    for (int n = 0; n < 4; ++n) {
      int key = kt * 64 + n * 16 + fr;
#pragma unroll
      for (int j = 0; j < 4; ++j) {
        float v = s[n][j] * SCALE_;
        if (key >= NN) v = -1e30f;
        s[n][j] = v;
        mx[j] = fmaxf(mx[j], v);
      }
    }
    for (int d = 1; d < 16; d <<= 1) {
#pragma unroll
      for (int j = 0; j < 4; ++j) mx[j] = fmaxf(mx[j], __shfl_xor(mx[j], d));
    }
    float corr[4];
#pragma unroll
    for (int j = 0; j < 4; ++j) {
      float mn = fmaxf(rowm[j], mx[j]);
      corr[j] = __expf(rowm[j] - mn);
      rowm[j] = mn;
    }
    float rs[4] = {};
#pragma unroll
    for (int n = 0; n < 4; ++n)
#pragma unroll
      for (int j = 0; j < 4; ++j) {
        float p = __expf(s[n][j] - rowm[j]);
        s[n][j] = p;
        rs[j] += p;
      }
    for (int d = 1; d < 16; d <<= 1) {
#pragma unroll
      for (int j = 0; j < 4; ++j) rs[j] += __shfl_xor(rs[j], d);
    }
#pragma unroll
    for (int j = 0; j < 4; ++j) rowl[j] = rowl[j] * corr[j] + rs[j];
#pragma unroll
    for (int n = 0; n < 4; ++n)
#pragma unroll
      for (int j = 0; j < 4; ++j) o[n][j] *= corr[j];

#pragma unroll
    for (int n = 0; n < 4; ++n)
#pragma unroll
      for (int j = 0; j < 4; ++j)
        Pls[w][fg * 4 + j][n * 16 + fr] = f2bf(s[n][j]);
    __syncthreads();

#pragma unroll
    for (int kk = 0; kk < 2; ++kk) {
      u16x8 pf = *(const u16x8*)&Pls[w][fr][kk * 32 + fg * 8];
#pragma unroll
      for (int n = 0; n < 4; ++n) {
        u16x8 vf = *(const u16x8*)&Vt[n * 16 + fr][kk * 32 + fg * 8];
        o[n] = mfma16(pf, vf, o[n]);
      }
    }
    __syncthreads();
  }

#pragma unroll
  for (int n = 0; n < 4; ++n)
#pragma unroll
    for (int j = 0; j < 4; ++j) {
      int dv = n * 16 + fr, q2 = w * 16 + fg * 4 + j;
      QdT[((size_t)bh * 64 + dv) * 64 + q2] = f2bf(o[n][j] / rowl[j]);
    }
}

// ---------------- Stage 2 ----------------
__global__ __launch_bounds__(256) void stage2_kernel(
    const u16* __restrict__ qkv, const u16* __restrict__ Qp,
    const u16* __restrict__ QdT, u16* __restrict__ AO)
{
  __shared__ u16 Qpl[64][72];
  __shared__ u16 Qdl[64][72];
  __shared__ u16 Pls[4][16][72];
  int id = blockIdx.x;
  int ntile = id % 10;
  int bh = id / 10, b = bh >> 4, h = bh & 15;
  int t = threadIdx.x, lane = t & 63, w = t >> 6;
  int fr = lane & 15, fg = lane >> 4;

#pragma unroll
  for (int i = 0; i < 2; ++i) {
    int g = t + i * 256;
    int row = g >> 3, cc = (g & 7) * 8;
    *(u16x8*)&Qpl[row][cc] = *(const u16x8*)(Qp + (size_t)(b * 64 + row) * CC + h * DD + cc);
    *(u16x8*)&Qdl[row][cc] = *(const u16x8*)(QdT + ((size_t)bh * 64 + row) * 64 + cc);
  }
  __syncthreads();

  int n0 = ntile * 64;
  int qrow = n0 + w * 16 + fr;
  int qc = qrow < NN ? qrow : NN - 1;
  const u16* Qb = qkv + (size_t)(b * NN + qc) * 3072 + h * DD;
  u16x8 qf0 = *(const u16x8*)(Qb + fg * 8);
  u16x8 qf1 = *(const u16x8*)(Qb + 32 + fg * 8);

  f32x4 s[4] = {};
#pragma unroll
  for (int kk = 0; kk < 2; ++kk) {
    u16x8 qf = kk ? qf1 : qf0;
#pragma unroll
    for (int n = 0; n < 4; ++n) {
      u16x8 bfrag = *(const u16x8*)&Qpl[n * 16 + fr][kk * 32 + fg * 8];
      s[n] = mfma16(qf, bfrag, s[n]);
    }
  }
  float mx[4] = {-1e30f, -1e30f, -1e30f, -1e30f};
#pragma unroll
  for (int n = 0; n < 4; ++n)
#pragma unroll
    for (int j = 0; j < 4; ++j) {
      float v = s[n][j] * SCALE_;
      s[n][j] = v;
      mx[j] = fmaxf(mx[j], v);
    }
  for (int d = 1; d < 16; d <<= 1) {
#pragma unroll
    for (int j = 0; j < 4; ++j) mx[j] = fmaxf(mx[j], __shfl_xor(mx[j], d));
  }
  float rs[4] = {};
#pragma unroll
  for (int n = 0; n < 4; ++n)
#pragma unroll
    for (int j = 0; j < 4; ++j) {
      float p = __expf(s[n][j] - mx[j]);
      s[n][j] = p;
      rs[j] += p;
    }
  for (int d = 1; d < 16; d <<= 1) {
#pragma unroll
    for (int j = 0; j < 4; ++j) rs[j] += __shfl_xor(rs[j], d);
  }

#pragma unroll
  for (int n = 0; n < 4; ++n)
#pragma unroll
    for (int j = 0; j < 4; ++j)
      Pls[w][fg * 4 + j][n * 16 + fr] = f2bf(s[n][j]);
  __syncthreads();

  f32x4 of[4] = {};
#pragma unroll
  for (int kk = 0; kk < 2; ++kk) {
    u16x8 pf = *(const u16x8*)&Pls[w][fr][kk * 32 + fg * 8];
#pragma unroll
    for (int n = 0; n < 4; ++n) {
      u16x8 qd = *(const u16x8*)&Qdl[n * 16 + fr][kk * 32 + fg * 8];
      of[n] = mfma16(pf, qd, of[n]);
    }
  }

#pragma unroll
  for (int n = 0; n < 4; ++n)
#pragma unroll
    for (int j = 0; j < 4; ++j) {
      int orow = n0 + w * 16 + fg * 4 + j;
      if (orow < NN)
        AO[(size_t)(b * NN + orow) * CC + h * DD + n * 16 + fr] = f2bf(of[n][j] / rs[j]);
    }
}

// ---------------- launch ----------------
extern "C" void kernel_launch(void* const* d_in, const int* in_sizes, int n_in,
                              void* d_out, int out_size, void* d_ws, size_t ws_size,
                              hipStream_t stream) {
  const float* X     = (const float*)d_in[0];
  const float* Wqkv  = (const float*)d_in[1];
  const float* Wproj = (const float*)d_in[2];
  const float* bproj = (const float*)d_in[3];

  char* ws = (char*)d_ws;
  u16* Xb  = (u16*)(ws + 0);            // 18464*1024*2 = 37,814,272
  u16* Wqb = (u16*)(ws + 37814272);     // 3072*1024*2  =  6,291,456
  u16* Wpb = (u16*)(ws + 44105728);     // 1024*1024*2  =  2,097,152
  u16* qkv = (u16*)(ws + 46202880);     // 18464*3072*2 = 113,442,816
  u16* Qpb = (u16*)(ws + 159645696);    // 32*64*1024*2 =  4,194,304
  u16* QdT = (u16*)(ws + 163840000);    // 512*64*64*2  =  4,194,304
  u16* AO  = (u16*)(ws + 168034304);    // 18464*1024*2 = 37,814,272

  cvt_kernel<<<2048, 256, 0, stream>>>(X, Xb, (BB * NN * CC) / 4);
  cvt_kernel<<<1024, 256, 0, stream>>>(Wqkv, Wqb, (3 * CC * CC) / 4);
  cvt_kernel<<<512, 256, 0, stream>>>(Wproj, Wpb, (CC * CC) / 4);

  // QKV: 4-phase interleaved 256x256 kernel (73 x 12 tiles), light barriers
  gemm_p4<<<73 * 12, 512, 0, stream>>>(Xb, Wqb, qkv, MM, 3 * CC, CC, 73, 12);

  pool_kernel<<<BB * 64, 256, 0, stream>>>(qkv, Qpb);
  stage1_kernel<<<BB * HH, 256, 0, stream>>>(qkv, Qpb, QdT);
  stage2_kernel<<<BB * HH * 10, 256, 0, stream>>>(qkv, Qpb, QdT, AO);

  // proj: proven round-3 structure (145 x 8 tiles) — in-run control
  gemm_bt2<<<145 * 8, 256, 0, stream>>>(AO, Wpb, nullptr, (float*)d_out, bproj,
                                        MM, CC, CC, 145, 8);
}